// Round 1
// baseline (24893.883 us; speedup 1.0000x reference)
//
#include <hip/hip_runtime.h>
#include <cstdint>
#include <cstddef>

#define NN   4096      // neurons
#define NE   131072    // edges
#define NBAT 8         // batch
#define NT   128       // timesteps
#define NV   8192      // vocab
#define NK   4096      // = NN (GEMM K)
#define NM   1024      // = NBAT*NT (GEMM M)
#define DECAYF 0.99f
#define COOP_BLOCKS 256
#define COOP_THREADS 512

typedef short bf16x8 __attribute__((ext_vector_type(8)));
typedef float f32x4 __attribute__((ext_vector_type(4)));
typedef unsigned short u16x8 __attribute__((ext_vector_type(8)));

__device__ __forceinline__ unsigned short f2bf(float f) {
  unsigned int u = __builtin_bit_cast(unsigned int, f);
  u = u + 0x7fffu + ((u >> 16) & 1u);   // round-to-nearest-even
  return (unsigned short)(u >> 16);
}

// ---------------- prologue: CSR build ----------------
__global__ void k_hist(const int* __restrict__ dst, int* __restrict__ cnt) {
  int e = blockIdx.x * 256 + threadIdx.x;
  if (e < NE) atomicAdd(&cnt[dst[e]], 1);
}

__global__ void k_scan(const int* __restrict__ cnt, int* __restrict__ row_ptr,
                       int* __restrict__ cursor) {
  __shared__ int lds[256];
  int tid = threadIdx.x;
  int base = tid * 16;
  int loc[16];
  int s = 0;
  #pragma unroll
  for (int i = 0; i < 16; ++i) { loc[i] = s; s += cnt[base + i]; }
  lds[tid] = s;
  __syncthreads();
  for (int off = 1; off < 256; off <<= 1) {
    int v = lds[tid];
    int a = (tid >= off) ? lds[tid - off] : 0;
    __syncthreads();
    lds[tid] = v + a;
    __syncthreads();
  }
  int myoff = (tid == 0) ? 0 : lds[tid - 1];
  #pragma unroll
  for (int i = 0; i < 16; ++i) {
    int rp = myoff + loc[i];
    row_ptr[base + i] = rp;
    cursor[base + i] = rp;
  }
  if (tid == 255) row_ptr[NN] = lds[255];
}

__global__ void k_build(const int* __restrict__ src, const int* __restrict__ dst,
                        const float* __restrict__ Gx, const float* __restrict__ Gy,
                        const float* __restrict__ Gs, int* __restrict__ cursor,
                        int* __restrict__ src_s, int* __restrict__ orig_s,
                        float* __restrict__ Gx_s, float* __restrict__ Gy_s,
                        float* __restrict__ Gs_s) {
  int e = blockIdx.x * 256 + threadIdx.x;
  if (e >= NE) return;
  int d = dst[e];
  int pos = atomicAdd(&cursor[d], 1);
  src_s[pos] = src[e];
  orig_s[pos] = e;
  Gx_s[pos] = Gx[e];
  Gy_s[pos] = Gy[e];
  Gs_s[pos] = Gs[e];
}

// Gather all embeddings into (T, N, B) layout; also init y0 = X[:,0,:]
__global__ void k_gatherX(const int* __restrict__ idx, const float* __restrict__ Wemb,
                          float* __restrict__ Xbuf, float* __restrict__ ybuf) {
  __shared__ float tile[256 * 9];   // +1 pad stride to kill bank conflicts
  int t = blockIdx.x >> 4;
  int nc = (blockIdx.x & 15) << 8;
  int tid = threadIdx.x;
  #pragma unroll
  for (int bb = 0; bb < 8; ++bb) {
    int row = idx[bb * NT + t];     // idx is (B,T)
    tile[tid * 9 + bb] = Wemb[(size_t)row * NN + nc + tid];
  }
  __syncthreads();
  float* dp = Xbuf + (size_t)t * (NN * NBAT) + (size_t)nc * NBAT;
  #pragma unroll
  for (int kk = 0; kk < 8; ++kk) dp[tid * 8 + kk] = tile[tid * 9 + kk];
  if (t == 0) {
    float* yp = ybuf + (size_t)nc * NBAT;
    #pragma unroll
    for (int kk = 0; kk < 8; ++kk) yp[tid * 8 + kk] = tile[tid * 9 + kk];
  }
}

__global__ void k_convW(const float* __restrict__ W, unsigned short* __restrict__ Wbf) {
  size_t base = ((size_t)blockIdx.x * 256 + threadIdx.x) * 8;
  float4 a = *(const float4*)(W + base);
  float4 b = *(const float4*)(W + base + 4);
  u16x8 hv;
  hv[0] = f2bf(a.x); hv[1] = f2bf(a.y); hv[2] = f2bf(a.z); hv[3] = f2bf(a.w);
  hv[4] = f2bf(b.x); hv[5] = f2bf(b.y); hv[6] = f2bf(b.z); hv[7] = f2bf(b.w);
  *(u16x8*)(Wbf + base) = hv;
}

// ---------------- grid barrier (sense via generation counter) ----------------
__device__ __forceinline__ void gridbar(int* bar, int nblk, int& gen) {
  __syncthreads();   // drains each wave's vmem ops (compiler emits vmcnt(0))
  if (threadIdx.x == 0) {
    // acq_rel agent-scope RMW: release side writes back dirty L2 (cross-XCD)
    int prev = __hip_atomic_fetch_add(&bar[0], 1, __ATOMIC_ACQ_REL, __HIP_MEMORY_SCOPE_AGENT);
    if (prev == nblk - 1) {
      __hip_atomic_store(&bar[0], 0, __ATOMIC_RELAXED, __HIP_MEMORY_SCOPE_AGENT);
      __hip_atomic_fetch_add(&bar[1], 1, __ATOMIC_RELEASE, __HIP_MEMORY_SCOPE_AGENT);
    } else {
      while (__hip_atomic_load(&bar[1], __ATOMIC_RELAXED, __HIP_MEMORY_SCOPE_AGENT) <= gen) {
        __builtin_amdgcn_s_sleep(2);
      }
    }
  }
  ++gen;
  __syncthreads();
  // every wave invalidates L1/L2 so post-barrier gathers see remote writes
  __builtin_amdgcn_fence(__ATOMIC_ACQUIRE, "agent");
}

// ---------------- persistent recurrence kernel ----------------
// thread mapping: g = b | h<<3 | n<<5  (b=batch lane, h=edge-strip, n=node)
__global__ __launch_bounds__(COOP_THREADS, 4) void k_loop(
    const int* __restrict__ row_ptr, const int* __restrict__ src_s,
    const float* __restrict__ Gx_s, const float* __restrict__ Gy_s,
    const float* __restrict__ Gs_s, float* __restrict__ sigma_s,
    const float* __restrict__ Xbuf, float* __restrict__ ybuf,
    float* __restrict__ xbuf, float* __restrict__ Abuf,
    unsigned short* __restrict__ Abf, int* bar,
    const int* __restrict__ orig_s, float* __restrict__ sig_out) {
  const int tid = threadIdx.x;
  const int g = blockIdx.x * COOP_THREADS + tid;
  const int b = g & 7;
  const int h = (g >> 3) & 3;
  const int n = g >> 5;
  const int rs = row_ptr[n];
  const int re = row_ptr[n + 1];
  const int nb8 = (n << 3) | b;
  const int nblk = gridDim.x;
  int gen = 0;

  for (int t = 0; t < NT; ++t) {
    const float* xp = Xbuf + (size_t)t * (NN * NBAT);
    #pragma unroll
    for (int layer = 0; layer < 2; ++layer) {
      // ---- S12: A[b,n] = sum x[b,src]*sigma ; hebbian ; sigma update ----
      {
        float xn = xp[nb8];
        float acc = 0.f;
        for (int j = rs + h; j < re; j += 4) {
          int s = src_s[j];
          float sg = sigma_s[j];
          float gs = Gs_s[j];
          float xv = xp[(s << 3) | b];
          float yv = ybuf[(s << 3) | b];
          acc = fmaf(xv, sg, acc);          // uses OLD sigma (matches ref)
          float p = yv * xn;                // y_t[b,src]*x_t[b,dst]
          p += __shfl_xor(p, 1);
          p += __shfl_xor(p, 2);
          p += __shfl_xor(p, 4);            // sum over 8 batch lanes
          if (b == 0) sigma_s[j] = (sg + p * 0.125f * gs) * DECAYF;
        }
        acc += __shfl_xor(acc, 8);
        acc += __shfl_xor(acc, 16);         // combine 4 edge-strips
        if (h == 0) Abuf[nb8] = acc;
      }
      gridbar(bar, nblk, gen);
      // ---- S3: y[b,n] = sum relu(A[b,src])*Gy ----
      {
        float acc = 0.f;
        for (int j = rs + h; j < re; j += 4) {
          int s = src_s[j];
          float gy = Gy_s[j];
          float av = Abuf[(s << 3) | b];
          acc = fmaf(fmaxf(av, 0.f), gy, acc);
        }
        acc += __shfl_xor(acc, 8);
        acc += __shfl_xor(acc, 16);
        if (h == 0) ybuf[nb8] = acc;
      }
      gridbar(bar, nblk, gen);
      // ---- S4: x[b,n] = relu(sum y[b,src]*Gx) ----
      {
        float acc = 0.f;
        for (int j = rs + h; j < re; j += 4) {
          int s = src_s[j];
          float gx = Gx_s[j];
          float yv = ybuf[(s << 3) | b];
          acc = fmaf(yv, gx, acc);
        }
        acc += __shfl_xor(acc, 8);
        acc += __shfl_xor(acc, 16);
        if (layer == 0) {
          if (h == 0) xbuf[nb8] = fmaxf(acc, 0.f);
        } else if (h == 0) {
          // xs output straight into GEMM A-matrix (bf16), row m = b*T+t
          Abf[(size_t)((b << 7) | t) * NK + n] = f2bf(fmaxf(acc, 0.f));
        }
      }
      if (layer == 0) {
        gridbar(bar, nblk, gen);
        xp = xbuf;
      }
      // no barrier after layer-2 S4: nothing before the next S12 barrier
      // reads Abf, and S4 reads nothing the next S12 writes.
    }
  }
  // epilogue: sigma back to original edge order (block-local rows only)
  __syncthreads();
  int jlo = row_ptr[blockIdx.x * 16];
  int jhi = row_ptr[blockIdx.x * 16 + 16];
  for (int j = jlo + tid; j < jhi; j += COOP_THREADS) sig_out[orig_s[j]] = sigma_s[j];
}

// ---------------- bf16 MFMA GEMM: C[m,v] = sum_k A[m,k]*Bw[v,k] + bias[v] ----------------
__global__ __launch_bounds__(256) void k_gemm(const unsigned short* __restrict__ A,
                                              const unsigned short* __restrict__ Bw,
                                              const float* __restrict__ bias,
                                              float* __restrict__ C) {
  __shared__ __align__(16) unsigned short As[128 * 32];
  __shared__ __align__(16) unsigned short Bs[128 * 32];
  const int m0 = blockIdx.y * 128;
  const int v0 = blockIdx.x * 128;
  const int wave = threadIdx.x >> 6;
  const int lane = threadIdx.x & 63;
  const int wm = wave >> 1;
  const int wv = wave & 1;
  f32x4 acc[4][4] = {};

  const int srow = lane >> 2;
  const int skc = (lane & 3) * 8;

  for (int k0 = 0; k0 < NK; k0 += 32) {
    #pragma unroll
    for (int c = 0; c < 2; ++c) {
      int chunk = wave * 2 + c;
      int row = chunk * 16 + srow;
      __builtin_amdgcn_global_load_lds(
          (const __attribute__((address_space(1))) void*)(A + (size_t)(m0 + row) * NK + k0 + skc),
          (__attribute__((address_space(3))) void*)(As + chunk * 512), 16, 0, 0);
      __builtin_amdgcn_global_load_lds(
          (const __attribute__((address_space(1))) void*)(Bw + (size_t)(v0 + row) * NK + k0 + skc),
          (__attribute__((address_space(3))) void*)(Bs + chunk * 512), 16, 0, 0);
    }
    __syncthreads();
    bf16x8 af[4], bq[4];
    #pragma unroll
    for (int mi = 0; mi < 4; ++mi)
      af[mi] = *(const bf16x8*)(As + ((wm * 64 + mi * 16 + (lane & 15)) * 32 + (lane >> 4) * 8));
    #pragma unroll
    for (int ni = 0; ni < 4; ++ni)
      bq[ni] = *(const bf16x8*)(Bs + ((wv * 64 + ni * 16 + (lane & 15)) * 32 + (lane >> 4) * 8));
    #pragma unroll
    for (int mi = 0; mi < 4; ++mi)
      #pragma unroll
      for (int ni = 0; ni < 4; ++ni)
        acc[mi][ni] = __builtin_amdgcn_mfma_f32_16x16x32_bf16(af[mi], bq[ni], acc[mi][ni], 0, 0, 0);
    __syncthreads();
  }

  #pragma unroll
  for (int mi = 0; mi < 4; ++mi) {
    int mrow = m0 + wm * 64 + mi * 16 + ((lane >> 4) << 2);
    #pragma unroll
    for (int ni = 0; ni < 4; ++ni) {
      int vcol = v0 + wv * 64 + ni * 16 + (lane & 15);
      float bs = bias[vcol];
      f32x4 a = acc[mi][ni];
      #pragma unroll
      for (int r = 0; r < 4; ++r) C[(size_t)(mrow + r) * NV + vcol] = a[r] + bs;
    }
  }
}

// ---------------- launch ----------------
extern "C" void kernel_launch(void* const* d_in, const int* in_sizes, int n_in,
                              void* d_out, int out_size, void* d_ws, size_t ws_size,
                              hipStream_t stream) {
  (void)in_sizes; (void)n_in; (void)out_size;
  const int*   idx  = (const int*)d_in[0];
  const int*   src  = (const int*)d_in[1];
  const int*   dst  = (const int*)d_in[2];
  const float* Wemb = (const float*)d_in[3];
  const float* Gx   = (const float*)d_in[4];
  const float* Gy   = (const float*)d_in[5];
  const float* Gs   = (const float*)d_in[6];
  const float* Wout = (const float*)d_in[7];
  const float* bout = (const float*)d_in[8];
  float* out = (float*)d_out;
  float* sig_out = out + (size_t)NM * NV;   // logits first, then sigma

  char* p = (char*)d_ws;
  int*   bar     = (int*)p;                    // 256 B
  int*   cnt     = (int*)(p + 256);            // 16 KB
  float* sigma_s = (float*)(p + 256 + 16384);  // 512 KB (zero-init region ends here)
  size_t off = 256 + 16384 + (size_t)NE * 4;
  const size_t msz = off;
  int*   row_ptr = (int*)(p + off); off += 16640;          // 4097 ints, padded
  int*   cursor  = (int*)(p + off); off += 16384;
  int*   src_s   = (int*)(p + off); off += (size_t)NE * 4;
  int*   orig_s  = (int*)(p + off); off += (size_t)NE * 4;
  float* Gx_s    = (float*)(p + off); off += (size_t)NE * 4;
  float* Gy_s    = (float*)(p + off); off += (size_t)NE * 4;
  float* Gs_s    = (float*)(p + off); off += (size_t)NE * 4;
  float* ybuf    = (float*)(p + off); off += (size_t)NN * NBAT * 4;
  float* xbuf    = (float*)(p + off); off += (size_t)NN * NBAT * 4;
  float* Abuf    = (float*)(p + off); off += (size_t)NN * NBAT * 4;
  float* Xbuf    = (float*)(p + off); off += (size_t)NT * NN * NBAT * 4;   // 16 MB
  unsigned short* Abf = (unsigned short*)(p + off); off += (size_t)NM * NK * 2; // 8 MB
  unsigned short* Wbf = (unsigned short*)(p + off); off += (size_t)NV * NK * 2; // 64 MB
  if (ws_size < off) return;   // ~92 MB required

  hipMemsetAsync(d_ws, 0, msz, stream);
  k_hist<<<NE / 256, 256, 0, stream>>>(dst, cnt);
  k_scan<<<1, 256, 0, stream>>>(cnt, row_ptr, cursor);
  k_build<<<NE / 256, 256, 0, stream>>>(src, dst, Gx, Gy, Gs, cursor,
                                        src_s, orig_s, Gx_s, Gy_s, Gs_s);
  k_gatherX<<<NT * 16, 256, 0, stream>>>(idx, Wemb, Xbuf, ybuf);
  k_convW<<<(NV * NK) / (256 * 8), 256, 0, stream>>>(Wout, Wbf);
  k_loop<<<COOP_BLOCKS, COOP_THREADS, 0, stream>>>(row_ptr, src_s, Gx_s, Gy_s, Gs_s,
      sigma_s, Xbuf, ybuf, xbuf, Abuf, Abf, bar, orig_s, sig_out);
  k_gemm<<<dim3(NV / 128, NM / 128), 256, 0, stream>>>(Abf, Wbf, bout, out);
}

// Round 2
// 5115.871 us; speedup vs baseline: 4.8660x; 4.8660x over previous
//
#include <hip/hip_runtime.h>
#include <cstdint>
#include <cstddef>

#define NN   4096      // neurons
#define NE   131072    // edges
#define NBAT 8         // batch
#define NT   128       // timesteps
#define NV   8192      // vocab
#define NK   4096      // = NN (GEMM K)
#define NM   1024      // = NBAT*NT (GEMM M)
#define DECAYF 0.99f
#define COOP_BLOCKS 256
#define COOP_THREADS 1024   // 8 batch x 8 strips x 16 nodes

typedef short bf16x8 __attribute__((ext_vector_type(8)));
typedef float f32x4 __attribute__((ext_vector_type(4)));
typedef unsigned short u16x8 __attribute__((ext_vector_type(8)));

__device__ __forceinline__ unsigned short f2bf(float f) {
  unsigned int u = __builtin_bit_cast(unsigned int, f);
  u = u + 0x7fffu + ((u >> 16) & 1u);   // round-to-nearest-even
  return (unsigned short)(u >> 16);
}

// Coherent (cross-XCD) access: sc0 sc1, bypasses L1/L2, served at the
// memory-side coherence point. No fences needed anywhere.
__device__ __forceinline__ float cload(const float* p) {
  return __hip_atomic_load(p, __ATOMIC_RELAXED, __HIP_MEMORY_SCOPE_AGENT);
}
__device__ __forceinline__ void cstore(float* p, float v) {
  __hip_atomic_store(p, v, __ATOMIC_RELAXED, __HIP_MEMORY_SCOPE_AGENT);
}

// ---------------- prologue: CSR build ----------------
__global__ void k_hist(const int* __restrict__ dst, int* __restrict__ cnt) {
  int e = blockIdx.x * 256 + threadIdx.x;
  if (e < NE) atomicAdd(&cnt[dst[e]], 1);
}

__global__ void k_scan(const int* __restrict__ cnt, int* __restrict__ row_ptr,
                       int* __restrict__ cursor) {
  __shared__ int lds[256];
  int tid = threadIdx.x;
  int base = tid * 16;
  int loc[16];
  int s = 0;
  #pragma unroll
  for (int i = 0; i < 16; ++i) { loc[i] = s; s += cnt[base + i]; }
  lds[tid] = s;
  __syncthreads();
  for (int off = 1; off < 256; off <<= 1) {
    int v = lds[tid];
    int a = (tid >= off) ? lds[tid - off] : 0;
    __syncthreads();
    lds[tid] = v + a;
    __syncthreads();
  }
  int myoff = (tid == 0) ? 0 : lds[tid - 1];
  #pragma unroll
  for (int i = 0; i < 16; ++i) {
    int rp = myoff + loc[i];
    row_ptr[base + i] = rp;
    cursor[base + i] = rp;
  }
  if (tid == 255) row_ptr[NN] = lds[255];
}

__global__ void k_build(const int* __restrict__ src, const int* __restrict__ dst,
                        const float* __restrict__ Gx, const float* __restrict__ Gy,
                        const float* __restrict__ Gs, int* __restrict__ cursor,
                        int* __restrict__ src_s, int* __restrict__ orig_s,
                        float* __restrict__ Gx_s, float* __restrict__ Gy_s,
                        float* __restrict__ Gs_s) {
  int e = blockIdx.x * 256 + threadIdx.x;
  if (e >= NE) return;
  int d = dst[e];
  int pos = atomicAdd(&cursor[d], 1);
  src_s[pos] = src[e];
  orig_s[pos] = e;
  Gx_s[pos] = Gx[e];
  Gy_s[pos] = Gy[e];
  Gs_s[pos] = Gs[e];
}

// Gather all embeddings into (T, N, B) layout; also init y0 = X[:,0,:]
__global__ void k_gatherX(const int* __restrict__ idx, const float* __restrict__ Wemb,
                          float* __restrict__ Xbuf, float* __restrict__ ybuf) {
  __shared__ float tile[256 * 9];   // +1 pad stride to kill bank conflicts
  int t = blockIdx.x >> 4;
  int nc = (blockIdx.x & 15) << 8;
  int tid = threadIdx.x;
  #pragma unroll
  for (int bb = 0; bb < 8; ++bb) {
    int row = idx[bb * NT + t];     // idx is (B,T)
    tile[tid * 9 + bb] = Wemb[(size_t)row * NN + nc + tid];
  }
  __syncthreads();
  float* dp = Xbuf + (size_t)t * (NN * NBAT) + (size_t)nc * NBAT;
  #pragma unroll
  for (int kk = 0; kk < 8; ++kk) dp[tid * 8 + kk] = tile[tid * 9 + kk];
  if (t == 0) {
    float* yp = ybuf + (size_t)nc * NBAT;
    #pragma unroll
    for (int kk = 0; kk < 8; ++kk) yp[tid * 8 + kk] = tile[tid * 9 + kk];
  }
}

__global__ void k_convW(const float* __restrict__ W, unsigned short* __restrict__ Wbf) {
  size_t base = ((size_t)blockIdx.x * 256 + threadIdx.x) * 8;
  float4 a = *(const float4*)(W + base);
  float4 b = *(const float4*)(W + base + 4);
  u16x8 hv;
  hv[0] = f2bf(a.x); hv[1] = f2bf(a.y); hv[2] = f2bf(a.z); hv[3] = f2bf(a.w);
  hv[4] = f2bf(b.x); hv[5] = f2bf(b.y); hv[6] = f2bf(b.z); hv[7] = f2bf(b.w);
  *(u16x8*)(Wbf + base) = hv;
}

// ---------------- grid barrier: no fences, no cache ops ----------------
// Hierarchical arrive: 8 sub-counters (128B apart) of 32 blocks each, then a
// master counter; final leader resets all, drains vmcnt, posts 8 per-group
// flip flags. State visibility is guaranteed because ALL cross-block state
// uses sc0sc1 write-through stores, drained by __syncthreads' vmcnt(0).
__device__ __forceinline__ void gridbar(int* bar, int& gen) {
  __syncthreads();
  if (threadIdx.x == 0) {
    const int grp = blockIdx.x & 7;
    int* ctr  = &bar[grp * 32];
    int* flip = &bar[grp * 32 + 8];
    int prev = __hip_atomic_fetch_add(ctr, 1, __ATOMIC_RELAXED, __HIP_MEMORY_SCOPE_AGENT);
    bool done = false;
    if (prev == (COOP_BLOCKS / 8) - 1) {
      int p2 = __hip_atomic_fetch_add(&bar[256], 1, __ATOMIC_RELAXED, __HIP_MEMORY_SCOPE_AGENT);
      if (p2 == 7) {    // final leader
        #pragma unroll
        for (int i = 0; i < 8; ++i)
          __hip_atomic_store(&bar[i * 32], 0, __ATOMIC_RELAXED, __HIP_MEMORY_SCOPE_AGENT);
        __hip_atomic_store(&bar[256], 0, __ATOMIC_RELAXED, __HIP_MEMORY_SCOPE_AGENT);
        __builtin_amdgcn_s_waitcnt(0);   // resets visible before flips
        #pragma unroll
        for (int i = 0; i < 8; ++i)
          __hip_atomic_store(&bar[i * 32 + 8], gen + 1, __ATOMIC_RELAXED, __HIP_MEMORY_SCOPE_AGENT);
        done = true;
      }
    }
    if (!done) {
      while (__hip_atomic_load(flip, __ATOMIC_RELAXED, __HIP_MEMORY_SCOPE_AGENT) <= gen) {
        __builtin_amdgcn_s_sleep(2);
      }
    }
  }
  ++gen;
  __syncthreads();
}

// ---------------- persistent recurrence kernel ----------------
// thread mapping: g = b | h<<3 | n<<6  (b=batch lane, h=edge-strip of 8, n=node)
// One wave = one node (8 batch x 8 strips). 16 nodes / block, 256 blocks.
__global__ __launch_bounds__(COOP_THREADS, 4) void k_loop(
    const int* __restrict__ row_ptr, const int* __restrict__ src_s,
    const float* __restrict__ Gx_s, const float* __restrict__ Gy_s,
    const float* __restrict__ Gs_s, float* __restrict__ sigma_s,
    const float* __restrict__ Xbuf, float* __restrict__ ybuf,
    float* __restrict__ xbuf, float* __restrict__ Abuf,
    unsigned short* __restrict__ Abf, int* bar,
    const int* __restrict__ orig_s, float* __restrict__ sig_out) {
  const int tid = threadIdx.x;
  const int g = blockIdx.x * COOP_THREADS + tid;
  const int b = g & 7;
  const int h = (g >> 3) & 7;
  const int n = g >> 6;
  const int rs = row_ptr[n];
  const int re = row_ptr[n + 1];
  const int nb8 = (n << 3) | b;
  int gen = 0;

  for (int t = 0; t < NT; ++t) {
    const float* xp = Xbuf + (size_t)t * (NN * NBAT);
    #pragma unroll
    for (int layer = 0; layer < 2; ++layer) {
      // ---- S12: A[b,n] = sum x[b,src]*sigma ; hebbian ; sigma update ----
      {
        float xn = (layer == 0) ? xp[nb8] : cload(&xbuf[nb8]);
        float acc = 0.f;
        for (int j = rs + h; j < re; j += 8) {
          int s = src_s[j];          // L1-resident (never invalidated)
          float sg = sigma_s[j];     // block-local, stays cached
          float gs = Gs_s[j];
          float xv = (layer == 0) ? xp[(s << 3) | b] : cload(&xbuf[(s << 3) | b]);
          float yv = cload(&ybuf[(s << 3) | b]);
          acc = fmaf(xv, sg, acc);          // uses OLD sigma (matches ref)
          float pv = yv * xn;               // y_t[b,src]*x_t[b,dst]
          pv += __shfl_xor(pv, 1);
          pv += __shfl_xor(pv, 2);
          pv += __shfl_xor(pv, 4);          // sum over 8 batch lanes
          if (b == 0) sigma_s[j] = (sg + pv * 0.125f * gs) * DECAYF;
        }
        acc += __shfl_xor(acc, 8);
        acc += __shfl_xor(acc, 16);
        acc += __shfl_xor(acc, 32);         // combine 8 edge-strips
        if (h == 0) cstore(&Abuf[nb8], acc);
      }
      gridbar(bar, gen);
      // ---- S3: y[b,n] = sum relu(A[b,src])*Gy ----
      {
        float acc = 0.f;
        for (int j = rs + h; j < re; j += 8) {
          int s = src_s[j];
          float gy = Gy_s[j];
          float av = cload(&Abuf[(s << 3) | b]);
          acc = fmaf(fmaxf(av, 0.f), gy, acc);
        }
        acc += __shfl_xor(acc, 8);
        acc += __shfl_xor(acc, 16);
        acc += __shfl_xor(acc, 32);
        if (h == 0) cstore(&ybuf[nb8], acc);
      }
      gridbar(bar, gen);
      // ---- S4: x[b,n] = relu(sum y[b,src]*Gx) ----
      {
        float acc = 0.f;
        for (int j = rs + h; j < re; j += 8) {
          int s = src_s[j];
          float gx = Gx_s[j];
          float yv = cload(&ybuf[(s << 3) | b]);
          acc = fmaf(yv, gx, acc);
        }
        acc += __shfl_xor(acc, 8);
        acc += __shfl_xor(acc, 16);
        acc += __shfl_xor(acc, 32);
        if (layer == 0) {
          if (h == 0) cstore(&xbuf[nb8], fmaxf(acc, 0.f));
        } else if (h == 0) {
          // xs output straight into GEMM A-matrix (bf16), row m = b*T+t
          Abf[(size_t)((b << 7) | t) * NK + n] = f2bf(fmaxf(acc, 0.f));
        }
      }
      if (layer == 0) {
        gridbar(bar, gen);
        xp = xbuf;
      }
      // no barrier after layer-2 S4 (nothing racing; see round-1 analysis)
    }
  }
  // epilogue: sigma back to original edge order (block-local rows only)
  __syncthreads();
  int jlo = row_ptr[blockIdx.x * 16];
  int jhi = row_ptr[blockIdx.x * 16 + 16];
  for (int j = jlo + tid; j < jhi; j += COOP_THREADS) sig_out[orig_s[j]] = sigma_s[j];
}

// ---------------- bf16 MFMA GEMM: C[m,v] = sum_k A[m,k]*Bw[v,k] + bias[v] ----------------
__global__ __launch_bounds__(256) void k_gemm(const unsigned short* __restrict__ A,
                                              const unsigned short* __restrict__ Bw,
                                              const float* __restrict__ bias,
                                              float* __restrict__ C) {
  __shared__ __align__(16) unsigned short As[128 * 32];
  __shared__ __align__(16) unsigned short Bs[128 * 32];
  const int m0 = blockIdx.y * 128;
  const int v0 = blockIdx.x * 128;
  const int wave = threadIdx.x >> 6;
  const int lane = threadIdx.x & 63;
  const int wm = wave >> 1;
  const int wv = wave & 1;
  f32x4 acc[4][4] = {};

  const int srow = lane >> 2;
  const int skc = (lane & 3) * 8;

  for (int k0 = 0; k0 < NK; k0 += 32) {
    #pragma unroll
    for (int c = 0; c < 2; ++c) {
      int chunk = wave * 2 + c;
      int row = chunk * 16 + srow;
      __builtin_amdgcn_global_load_lds(
          (const __attribute__((address_space(1))) void*)(A + (size_t)(m0 + row) * NK + k0 + skc),
          (__attribute__((address_space(3))) void*)(As + chunk * 512), 16, 0, 0);
      __builtin_amdgcn_global_load_lds(
          (const __attribute__((address_space(1))) void*)(Bw + (size_t)(v0 + row) * NK + k0 + skc),
          (__attribute__((address_space(3))) void*)(Bs + chunk * 512), 16, 0, 0);
    }
    __syncthreads();
    bf16x8 af[4], bq[4];
    #pragma unroll
    for (int mi = 0; mi < 4; ++mi)
      af[mi] = *(const bf16x8*)(As + ((wm * 64 + mi * 16 + (lane & 15)) * 32 + (lane >> 4) * 8));
    #pragma unroll
    for (int ni = 0; ni < 4; ++ni)
      bq[ni] = *(const bf16x8*)(Bs + ((wv * 64 + ni * 16 + (lane & 15)) * 32 + (lane >> 4) * 8));
    #pragma unroll
    for (int mi = 0; mi < 4; ++mi)
      #pragma unroll
      for (int ni = 0; ni < 4; ++ni)
        acc[mi][ni] = __builtin_amdgcn_mfma_f32_16x16x32_bf16(af[mi], bq[ni], acc[mi][ni], 0, 0, 0);
    __syncthreads();
  }

  #pragma unroll
  for (int mi = 0; mi < 4; ++mi) {
    int mrow = m0 + wm * 64 + mi * 16 + ((lane >> 4) << 2);
    #pragma unroll
    for (int ni = 0; ni < 4; ++ni) {
      int vcol = v0 + wv * 64 + ni * 16 + (lane & 15);
      float bs = bias[vcol];
      f32x4 a = acc[mi][ni];
      #pragma unroll
      for (int r = 0; r < 4; ++r) C[(size_t)(mrow + r) * NV + vcol] = a[r] + bs;
    }
  }
}

// ---------------- launch ----------------
extern "C" void kernel_launch(void* const* d_in, const int* in_sizes, int n_in,
                              void* d_out, int out_size, void* d_ws, size_t ws_size,
                              hipStream_t stream) {
  (void)in_sizes; (void)n_in; (void)out_size;
  const int*   idx  = (const int*)d_in[0];
  const int*   src  = (const int*)d_in[1];
  const int*   dst  = (const int*)d_in[2];
  const float* Wemb = (const float*)d_in[3];
  const float* Gx   = (const float*)d_in[4];
  const float* Gy   = (const float*)d_in[5];
  const float* Gs   = (const float*)d_in[6];
  const float* Wout = (const float*)d_in[7];
  const float* bout = (const float*)d_in[8];
  float* out = (float*)d_out;
  float* sig_out = out + (size_t)NM * NV;   // logits first, then sigma

  char* p = (char*)d_ws;
  int*   bar     = (int*)p;                      // 2 KB (261 ints used, padded)
  int*   cnt     = (int*)(p + 2048);             // 16 KB
  float* sigma_s = (float*)(p + 2048 + 16384);   // 512 KB (zero-init region ends here)
  size_t off = 2048 + 16384 + (size_t)NE * 4;
  const size_t msz = off;
  int*   row_ptr = (int*)(p + off); off += 16640;          // 4097 ints, padded
  int*   cursor  = (int*)(p + off); off += 16384;
  int*   src_s   = (int*)(p + off); off += (size_t)NE * 4;
  int*   orig_s  = (int*)(p + off); off += (size_t)NE * 4;
  float* Gx_s    = (float*)(p + off); off += (size_t)NE * 4;
  float* Gy_s    = (float*)(p + off); off += (size_t)NE * 4;
  float* Gs_s    = (float*)(p + off); off += (size_t)NE * 4;
  float* ybuf    = (float*)(p + off); off += (size_t)NN * NBAT * 4;
  float* xbuf    = (float*)(p + off); off += (size_t)NN * NBAT * 4;
  float* Abuf    = (float*)(p + off); off += (size_t)NN * NBAT * 4;
  float* Xbuf    = (float*)(p + off); off += (size_t)NT * NN * NBAT * 4;   // 16 MB
  unsigned short* Abf = (unsigned short*)(p + off); off += (size_t)NM * NK * 2; // 8 MB
  unsigned short* Wbf = (unsigned short*)(p + off); off += (size_t)NV * NK * 2; // 64 MB
  if (ws_size < off) return;   // ~92 MB required

  hipMemsetAsync(d_ws, 0, msz, stream);
  k_hist<<<NE / 256, 256, 0, stream>>>(dst, cnt);
  k_scan<<<1, 256, 0, stream>>>(cnt, row_ptr, cursor);
  k_build<<<NE / 256, 256, 0, stream>>>(src, dst, Gx, Gy, Gs, cursor,
                                        src_s, orig_s, Gx_s, Gy_s, Gs_s);
  k_gatherX<<<NT * 16, 256, 0, stream>>>(idx, Wemb, Xbuf, ybuf);
  k_convW<<<(NV * NK) / (256 * 8), 256, 0, stream>>>(Wout, Wbf);
  k_loop<<<COOP_BLOCKS, COOP_THREADS, 0, stream>>>(row_ptr, src_s, Gx_s, Gy_s, Gs_s,
      sigma_s, Xbuf, ybuf, xbuf, Abuf, Abf, bar, orig_s, sig_out);
  k_gemm<<<dim3(NV / 128, NM / 128), 256, 0, stream>>>(Abf, Wbf, bout, out);
}

// Round 3
// 3398.682 us; speedup vs baseline: 7.3246x; 1.5053x over previous
//
#include <hip/hip_runtime.h>
#include <cstdint>
#include <cstddef>

#define NN   4096      // neurons
#define NE   131072    // edges
#define NBAT 8         // batch
#define NT   128       // timesteps
#define NV   8192      // vocab
#define NK   4096      // = NN (GEMM K)
#define NM   1024      // = NBAT*NT (GEMM M)
#define DECAYF 0.99f
#define COOP_BLOCKS 256
#define COOP_THREADS 1024   // 8 batch x 8 strips x 16 nodes
#define NBARRIERS (NT * 5)  // 5 grid barriers per timestep

typedef short bf16x8 __attribute__((ext_vector_type(8)));
typedef float f32x4 __attribute__((ext_vector_type(4)));
typedef unsigned short u16x8 __attribute__((ext_vector_type(8)));

__device__ __forceinline__ unsigned short f2bf(float f) {
  unsigned int u = __builtin_bit_cast(unsigned int, f);
  u = u + 0x7fffu + ((u >> 16) & 1u);   // round-to-nearest-even
  return (unsigned short)(u >> 16);
}

// Coherent (cross-XCD) access: sc0 sc1, bypasses L1/L2, served at the
// memory-side coherence point. No fences needed anywhere.
__device__ __forceinline__ float cload(const float* p) {
  return __hip_atomic_load(p, __ATOMIC_RELAXED, __HIP_MEMORY_SCOPE_AGENT);
}
__device__ __forceinline__ void cstore(float* p, float v) {
  __hip_atomic_store(p, v, __ATOMIC_RELAXED, __HIP_MEMORY_SCOPE_AGENT);
}
__device__ __forceinline__ int cloadi(const int* p) {
  return __hip_atomic_load(p, __ATOMIC_RELAXED, __HIP_MEMORY_SCOPE_AGENT);
}
__device__ __forceinline__ void cstorei(int* p, int v) {
  __hip_atomic_store(p, v, __ATOMIC_RELAXED, __HIP_MEMORY_SCOPE_AGENT);
}

// ---------------- prologue: CSR build ----------------
__global__ void k_hist(const int* __restrict__ dst, int* __restrict__ cnt) {
  int e = blockIdx.x * 256 + threadIdx.x;
  if (e < NE) atomicAdd(&cnt[dst[e]], 1);
}

__global__ void k_scan(const int* __restrict__ cnt, int* __restrict__ row_ptr,
                       int* __restrict__ cursor) {
  __shared__ int lds[256];
  int tid = threadIdx.x;
  int base = tid * 16;
  int loc[16];
  int s = 0;
  #pragma unroll
  for (int i = 0; i < 16; ++i) { loc[i] = s; s += cnt[base + i]; }
  lds[tid] = s;
  __syncthreads();
  for (int off = 1; off < 256; off <<= 1) {
    int v = lds[tid];
    int a = (tid >= off) ? lds[tid - off] : 0;
    __syncthreads();
    lds[tid] = v + a;
    __syncthreads();
  }
  int myoff = (tid == 0) ? 0 : lds[tid - 1];
  #pragma unroll
  for (int i = 0; i < 16; ++i) {
    int rp = myoff + loc[i];
    row_ptr[base + i] = rp;
    cursor[base + i] = rp;
  }
  if (tid == 255) row_ptr[NN] = lds[255];
}

__global__ void k_build(const int* __restrict__ src, const int* __restrict__ dst,
                        const float* __restrict__ Gx, const float* __restrict__ Gy,
                        const float* __restrict__ Gs, int* __restrict__ cursor,
                        int* __restrict__ src_s, int* __restrict__ orig_s,
                        float* __restrict__ Gx_s, float* __restrict__ Gy_s,
                        float* __restrict__ Gs_s) {
  int e = blockIdx.x * 256 + threadIdx.x;
  if (e >= NE) return;
  int d = dst[e];
  int pos = atomicAdd(&cursor[d], 1);
  src_s[pos] = src[e];
  orig_s[pos] = e;
  Gx_s[pos] = Gx[e];
  Gy_s[pos] = Gy[e];
  Gs_s[pos] = Gs[e];
}

// Gather all embeddings into (T, N, B) layout; also init y0 = X[:,0,:]
__global__ void k_gatherX(const int* __restrict__ idx, const float* __restrict__ Wemb,
                          float* __restrict__ Xbuf, float* __restrict__ ybuf) {
  __shared__ float tile[256 * 9];   // +1 pad stride to kill bank conflicts
  int t = blockIdx.x >> 4;
  int nc = (blockIdx.x & 15) << 8;
  int tid = threadIdx.x;
  #pragma unroll
  for (int bb = 0; bb < 8; ++bb) {
    int row = idx[bb * NT + t];     // idx is (B,T)
    tile[tid * 9 + bb] = Wemb[(size_t)row * NN + nc + tid];
  }
  __syncthreads();
  float* dp = Xbuf + (size_t)t * (NN * NBAT) + (size_t)nc * NBAT;
  #pragma unroll
  for (int kk = 0; kk < 8; ++kk) dp[tid * 8 + kk] = tile[tid * 9 + kk];
  if (t == 0) {
    float* yp = ybuf + (size_t)nc * NBAT;
    #pragma unroll
    for (int kk = 0; kk < 8; ++kk) yp[tid * 8 + kk] = tile[tid * 9 + kk];
  }
}

__global__ void k_convW(const float* __restrict__ W, unsigned short* __restrict__ Wbf) {
  size_t base = ((size_t)blockIdx.x * 256 + threadIdx.x) * 8;
  float4 a = *(const float4*)(W + base);
  float4 b = *(const float4*)(W + base + 4);
  u16x8 hv;
  hv[0] = f2bf(a.x); hv[1] = f2bf(a.y); hv[2] = f2bf(a.z); hv[3] = f2bf(a.w);
  hv[4] = f2bf(b.x); hv[5] = f2bf(b.y); hv[6] = f2bf(b.z); hv[7] = f2bf(b.w);
  *(u16x8*)(Wbf + base) = hv;
}

// ---------------- grid barrier: store-arrive + master poller ----------------
// bar[0..255]   : per-block monotone arrive generation (worker leader stores)
// bar[320]      : monotone release generation (master stores)
// All sc0sc1; data visibility: cross-block data uses sc0sc1 write-through,
// drained to the coherence point by __syncthreads' vmcnt(0) BEFORE the
// arrive store issues. Master sees arrive==g for all => all data visible.
__device__ __forceinline__ void gridbar(int* bar, int& gen) {
  __syncthreads();
  if (threadIdx.x == 0) {
    cstorei(&bar[blockIdx.x], gen + 1);
    while (cloadi(&bar[320]) <= gen) __builtin_amdgcn_s_sleep(1);
  }
  ++gen;
  __syncthreads();
}

// ---------------- persistent recurrence kernel ----------------
// Worker blocks 0..255; block 256 = barrier master (wave 0 only).
// Worker mapping: g = b | h<<3 | n<<6 (b=batch lane, h=edge-strip, n=node).
// One wave = one node (8 batch x 8 strips). 16 nodes / block.
__global__ __launch_bounds__(COOP_THREADS, 8) void k_loop(
    const int* __restrict__ row_ptr, const int* __restrict__ src_s,
    const float* __restrict__ Gx_s, const float* __restrict__ Gy_s,
    const float* __restrict__ Gs_s, float* __restrict__ sigma_s,
    const float* __restrict__ Xbuf, float* __restrict__ ybuf,
    float* __restrict__ xbuf, float* __restrict__ Abuf,
    unsigned short* __restrict__ Abf, int* bar,
    const int* __restrict__ orig_s, float* __restrict__ sig_out) {
  if (blockIdx.x == COOP_BLOCKS) {
    // ---- barrier master: wave 0 polls 256 arrive flags, posts release ----
    if (threadIdx.x < 64) {
      const int lane = threadIdx.x;
      for (int g = 1; g <= NBARRIERS; ++g) {
        for (;;) {
          int v0 = cloadi(&bar[lane * 4 + 0]);
          int v1 = cloadi(&bar[lane * 4 + 1]);
          int v2 = cloadi(&bar[lane * 4 + 2]);
          int v3 = cloadi(&bar[lane * 4 + 3]);
          int m = min(min(v0, v1), min(v2, v3));
          #pragma unroll
          for (int d = 1; d < 64; d <<= 1) m = min(m, __shfl_xor(m, d));
          if (m >= g) break;
        }
        if (lane == 0) cstorei(&bar[320], g);
      }
    }
    return;
  }

  const int tid = threadIdx.x;
  const int g = blockIdx.x * COOP_THREADS + tid;
  const int b = g & 7;
  const int h = (g >> 3) & 7;
  const int n = g >> 6;
  const int rs = row_ptr[n];
  const int re = row_ptr[n + 1];
  const int nb8 = (n << 3) | b;
  int gen = 0;

  for (int t = 0; t < NT; ++t) {
    const float* xp = Xbuf + (size_t)t * (NN * NBAT);
    #pragma unroll
    for (int layer = 0; layer < 2; ++layer) {
      // ---- S12: A[b,n] = sum x[b,src]*sigma ; hebbian ; sigma update ----
      {
        float xn = (layer == 0) ? xp[nb8] : cload(&xbuf[nb8]);
        float acc = 0.f;
        for (int j = rs + h; j < re; j += 32) {
          int jj[4], sv[4];
          float sg[4], gs[4], xv[4], yv[4];
          bool act[4];
          #pragma unroll
          for (int u = 0; u < 4; ++u) {
            int jc = j + (u << 3);
            act[u] = jc < re;
            jj[u] = act[u] ? jc : j;     // clamped-safe index
          }
          #pragma unroll
          for (int u = 0; u < 4; ++u) sv[u] = src_s[jj[u]];
          #pragma unroll
          for (int u = 0; u < 4; ++u) {
            float sgu = sigma_s[jj[u]];
            float gsu = Gs_s[jj[u]];
            sg[u] = act[u] ? sgu : 0.f;
            gs[u] = act[u] ? gsu : 0.f;
          }
          #pragma unroll
          for (int u = 0; u < 4; ++u) {
            int sb = (sv[u] << 3) | b;
            xv[u] = (layer == 0) ? xp[sb] : cload(&xbuf[sb]);
            yv[u] = cload(&ybuf[sb]);
          }
          #pragma unroll
          for (int u = 0; u < 4; ++u) {
            acc = fmaf(xv[u], sg[u], acc);      // OLD sigma (matches ref)
            float pv = yv[u] * xn;              // y_t[b,src]*x_t[b,dst]
            pv += __shfl_xor(pv, 1);
            pv += __shfl_xor(pv, 2);
            pv += __shfl_xor(pv, 4);            // sum over 8 batch lanes
            if (b == 0 && act[u])
              sigma_s[jj[u]] = (sg[u] + pv * 0.125f * gs[u]) * DECAYF;
          }
        }
        acc += __shfl_xor(acc, 8);
        acc += __shfl_xor(acc, 16);
        acc += __shfl_xor(acc, 32);             // combine 8 edge-strips
        if (h == 0) cstore(&Abuf[nb8], acc);
      }
      gridbar(bar, gen);
      // ---- S3: y[b,n] = sum relu(A[b,src])*Gy ----
      {
        float acc = 0.f;
        for (int j = rs + h; j < re; j += 32) {
          int jj[4], sv[4];
          float gy[4], av[4];
          bool act[4];
          #pragma unroll
          for (int u = 0; u < 4; ++u) {
            int jc = j + (u << 3);
            act[u] = jc < re;
            jj[u] = act[u] ? jc : j;
          }
          #pragma unroll
          for (int u = 0; u < 4; ++u) sv[u] = src_s[jj[u]];
          #pragma unroll
          for (int u = 0; u < 4; ++u) {
            float gyu = Gy_s[jj[u]];
            gy[u] = act[u] ? gyu : 0.f;
          }
          #pragma unroll
          for (int u = 0; u < 4; ++u) av[u] = cload(&Abuf[(sv[u] << 3) | b]);
          #pragma unroll
          for (int u = 0; u < 4; ++u) acc = fmaf(fmaxf(av[u], 0.f), gy[u], acc);
        }
        acc += __shfl_xor(acc, 8);
        acc += __shfl_xor(acc, 16);
        acc += __shfl_xor(acc, 32);
        if (h == 0) cstore(&ybuf[nb8], acc);
      }
      gridbar(bar, gen);
      // ---- S4: x[b,n] = relu(sum y[b,src]*Gx) ----
      {
        float acc = 0.f;
        for (int j = rs + h; j < re; j += 32) {
          int jj[4], sv[4];
          float gx[4], yv[4];
          bool act[4];
          #pragma unroll
          for (int u = 0; u < 4; ++u) {
            int jc = j + (u << 3);
            act[u] = jc < re;
            jj[u] = act[u] ? jc : j;
          }
          #pragma unroll
          for (int u = 0; u < 4; ++u) sv[u] = src_s[jj[u]];
          #pragma unroll
          for (int u = 0; u < 4; ++u) {
            float gxu = Gx_s[jj[u]];
            gx[u] = act[u] ? gxu : 0.f;
          }
          #pragma unroll
          for (int u = 0; u < 4; ++u) yv[u] = cload(&ybuf[(sv[u] << 3) | b]);
          #pragma unroll
          for (int u = 0; u < 4; ++u) acc = fmaf(yv[u], gx[u], acc);
        }
        acc += __shfl_xor(acc, 8);
        acc += __shfl_xor(acc, 16);
        acc += __shfl_xor(acc, 32);
        if (layer == 0) {
          if (h == 0) cstore(&xbuf[nb8], fmaxf(acc, 0.f));
        } else if (h == 0) {
          // xs output straight into GEMM A-matrix (bf16), row m = b*T+t
          Abf[(size_t)((b << 7) | t) * NK + n] = f2bf(fmaxf(acc, 0.f));
        }
      }
      if (layer == 0) {
        gridbar(bar, gen);
        xp = xbuf;
      }
      // no barrier after layer-2 S4: next step's x comes from Xbuf, and y/sigma
      // are produced before the next barrier; Abf is consumed post-kernel.
    }
  }
  // epilogue: sigma back to original edge order (block-local rows only)
  __syncthreads();
  int jlo = row_ptr[blockIdx.x * 16];
  int jhi = row_ptr[blockIdx.x * 16 + 16];
  for (int j = jlo + tid; j < jhi; j += COOP_THREADS) sig_out[orig_s[j]] = sigma_s[j];
}

// ---------------- bf16 MFMA GEMM: C[m,v] = sum_k A[m,k]*Bw[v,k] + bias[v] ----------------
__global__ __launch_bounds__(256) void k_gemm(const unsigned short* __restrict__ A,
                                              const unsigned short* __restrict__ Bw,
                                              const float* __restrict__ bias,
                                              float* __restrict__ C) {
  __shared__ __align__(16) unsigned short As[128 * 32];
  __shared__ __align__(16) unsigned short Bs[128 * 32];
  const int m0 = blockIdx.y * 128;
  const int v0 = blockIdx.x * 128;
  const int wave = threadIdx.x >> 6;
  const int lane = threadIdx.x & 63;
  const int wm = wave >> 1;
  const int wv = wave & 1;
  f32x4 acc[4][4] = {};

  const int srow = lane >> 2;
  const int skc = (lane & 3) * 8;

  for (int k0 = 0; k0 < NK; k0 += 32) {
    #pragma unroll
    for (int c = 0; c < 2; ++c) {
      int chunk = wave * 2 + c;
      int row = chunk * 16 + srow;
      __builtin_amdgcn_global_load_lds(
          (const __attribute__((address_space(1))) void*)(A + (size_t)(m0 + row) * NK + k0 + skc),
          (__attribute__((address_space(3))) void*)(As + chunk * 512), 16, 0, 0);
      __builtin_amdgcn_global_load_lds(
          (const __attribute__((address_space(1))) void*)(Bw + (size_t)(v0 + row) * NK + k0 + skc),
          (__attribute__((address_space(3))) void*)(Bs + chunk * 512), 16, 0, 0);
    }
    __syncthreads();
    bf16x8 af[4], bq[4];
    #pragma unroll
    for (int mi = 0; mi < 4; ++mi)
      af[mi] = *(const bf16x8*)(As + ((wm * 64 + mi * 16 + (lane & 15)) * 32 + (lane >> 4) * 8));
    #pragma unroll
    for (int ni = 0; ni < 4; ++ni)
      bq[ni] = *(const bf16x8*)(Bs + ((wv * 64 + ni * 16 + (lane & 15)) * 32 + (lane >> 4) * 8));
    #pragma unroll
    for (int mi = 0; mi < 4; ++mi)
      #pragma unroll
      for (int ni = 0; ni < 4; ++ni)
        acc[mi][ni] = __builtin_amdgcn_mfma_f32_16x16x32_bf16(af[mi], bq[ni], acc[mi][ni], 0, 0, 0);
    __syncthreads();
  }

  #pragma unroll
  for (int mi = 0; mi < 4; ++mi) {
    int mrow = m0 + wm * 64 + mi * 16 + ((lane >> 4) << 2);
    #pragma unroll
    for (int ni = 0; ni < 4; ++ni) {
      int vcol = v0 + wv * 64 + ni * 16 + (lane & 15);
      float bs = bias[vcol];
      f32x4 a = acc[mi][ni];
      #pragma unroll
      for (int r = 0; r < 4; ++r) C[(size_t)(mrow + r) * NV + vcol] = a[r] + bs;
    }
  }
}

// ---------------- launch ----------------
extern "C" void kernel_launch(void* const* d_in, const int* in_sizes, int n_in,
                              void* d_out, int out_size, void* d_ws, size_t ws_size,
                              hipStream_t stream) {
  (void)in_sizes; (void)n_in; (void)out_size;
  const int*   idx  = (const int*)d_in[0];
  const int*   src  = (const int*)d_in[1];
  const int*   dst  = (const int*)d_in[2];
  const float* Wemb = (const float*)d_in[3];
  const float* Gx   = (const float*)d_in[4];
  const float* Gy   = (const float*)d_in[5];
  const float* Gs   = (const float*)d_in[6];
  const float* Wout = (const float*)d_in[7];
  const float* bout = (const float*)d_in[8];
  float* out = (float*)d_out;
  float* sig_out = out + (size_t)NM * NV;   // logits first, then sigma

  char* p = (char*)d_ws;
  int*   bar     = (int*)p;                      // 2 KB (arrive[256] + release)
  int*   cnt     = (int*)(p + 2048);             // 16 KB
  float* sigma_s = (float*)(p + 2048 + 16384);   // 512 KB (zero-init region ends here)
  size_t off = 2048 + 16384 + (size_t)NE * 4;
  const size_t msz = off;
  int*   row_ptr = (int*)(p + off); off += 16640;          // 4097 ints, padded
  int*   cursor  = (int*)(p + off); off += 16384;
  int*   src_s   = (int*)(p + off); off += (size_t)NE * 4;
  int*   orig_s  = (int*)(p + off); off += (size_t)NE * 4;
  float* Gx_s    = (float*)(p + off); off += (size_t)NE * 4;
  float* Gy_s    = (float*)(p + off); off += (size_t)NE * 4;
  float* Gs_s    = (float*)(p + off); off += (size_t)NE * 4;
  float* ybuf    = (float*)(p + off); off += (size_t)NN * NBAT * 4;
  float* xbuf    = (float*)(p + off); off += (size_t)NN * NBAT * 4;
  float* Abuf    = (float*)(p + off); off += (size_t)NN * NBAT * 4;
  float* Xbuf    = (float*)(p + off); off += (size_t)NT * NN * NBAT * 4;   // 16 MB
  unsigned short* Abf = (unsigned short*)(p + off); off += (size_t)NM * NK * 2; // 8 MB
  unsigned short* Wbf = (unsigned short*)(p + off); off += (size_t)NV * NK * 2; // 64 MB
  if (ws_size < off) return;   // ~92 MB required

  hipMemsetAsync(d_ws, 0, msz, stream);
  k_hist<<<NE / 256, 256, 0, stream>>>(dst, cnt);
  k_scan<<<1, 256, 0, stream>>>(cnt, row_ptr, cursor);
  k_build<<<NE / 256, 256, 0, stream>>>(src, dst, Gx, Gy, Gs, cursor,
                                        src_s, orig_s, Gx_s, Gy_s, Gs_s);
  k_gatherX<<<NT * 16, 256, 0, stream>>>(idx, Wemb, Xbuf, ybuf);
  k_convW<<<(NV * NK) / (256 * 8), 256, 0, stream>>>(Wout, Wbf);
  k_loop<<<COOP_BLOCKS + 1, COOP_THREADS, 0, stream>>>(row_ptr, src_s, Gx_s, Gy_s, Gs_s,
      sigma_s, Xbuf, ybuf, xbuf, Abuf, Abf, bar, orig_s, sig_out);
  k_gemm<<<dim3(NV / 128, NM / 128), 256, 0, stream>>>(Abf, Wbf, bout, out);
}